// Round 6
// baseline (285.724 us; speedup 1.0000x reference)
//
#include <hip/hip_runtime.h>

#define N_NODES 100000
#define N_EDGES 1600000
#define D_FEAT  64

#define RSHIFT 8
#define RPB    256                              // rows per bucket
#define NBK    ((N_NODES + RPB - 1) / RPB)      // 391 row-buckets
#define CAP    5120                             // bucket edge capacity
#define EPB    4096                             // edges per bin block
#define KBLK   ((N_EDGES + EPB - 1) / EPB)      // 391 bin blocks
#define OROW   (NBK + 1)
#define CVB    ((N_NODES * D_FEAT / 4 + 1023) / 1024)  // 1563 convert blocks
#define SB2    ((N_NODES + 63) / 64)            // 1563 spmm blocks (64 rows each)

typedef float f32x2 __attribute__((ext_vector_type(2)));

__device__ __forceinline__ unsigned short f2bf(float f) {
  union { float f; unsigned int i; } v; v.f = f;
  unsigned int b = v.i;
  return (unsigned short)((b + 0x7FFFu + ((b >> 16) & 1u)) >> 16);  // RNE
}
__device__ __forceinline__ float ulo(int u) { return __int_as_float(u << 16); }
__device__ __forceinline__ float uhi(int u) { return __int_as_float(u & 0xFFFF0000); }
__device__ __forceinline__ f32x2 upk(int u) {  // {elem0, elem1} of a bf16 pair
  f32x2 r; r.x = ulo(u); r.y = uhi(u); return r;
}
__device__ __forceinline__ int pk(float a, float b) {
  return (int)f2bf(a) | ((int)f2bf(b) << 16);
}

// ---- fused: blocks [0,KBLK) bin edges; blocks [KBLK, KBLK+CVB) convert x ----
__global__ __launch_bounds__(1024) void convert_bin(
    const float4* __restrict__ xin, ushort4* __restrict__ xout,
    const int* __restrict__ erow, const int* __restrict__ ecol,
    const float* __restrict__ evals, int2* __restrict__ tmp,
    int* __restrict__ offs) {
  __shared__ int hist[NBK];
  __shared__ int sc[NBK];
  int t = threadIdx.x;
  int k = blockIdx.x;
  if (k >= KBLK) {                       // ---- convert path ----
    int i = (k - KBLK) * 1024 + t;
    if (i < N_NODES * D_FEAT / 4) {
      float4 v = xin[i];
      ushort4 o;
      o.x = f2bf(v.x); o.y = f2bf(v.y); o.z = f2bf(v.z); o.w = f2bf(v.w);
      xout[i] = o;
    }
    return;
  }
  // ---- bin path: block-local counting sort of 4096 edges by bucket ----
  if (t < NBK) hist[t] = 0;
  __syncthreads();
  int base = k * EPB;
  int nk = N_EDGES - base; if (nk > EPB) nk = EPB;
  int key[4], vb[4], rk[4], bk[4];
#pragma unroll
  for (int j = 0; j < 4; ++j) {
    int li = j * 1024 + t;
    bk[j] = -1;
    if (li < nk) {
      int e = base + li;
      int r = erow[e];
      key[j] = ((r & (RPB - 1)) << 17) | ecol[e];
      vb[j]  = __float_as_int(evals[e]);
      bk[j]  = r >> RSHIFT;
      rk[j]  = atomicAdd(&hist[bk[j]], 1);
    }
  }
  __syncthreads();
  if (t < NBK) sc[t] = hist[t];
  __syncthreads();
  for (int off = 1; off < NBK; off <<= 1) {
    int u = (t >= off && t < NBK) ? sc[t - off] : 0;
    __syncthreads();
    if (t < NBK) sc[t] += u;
    __syncthreads();
  }
  if (t < NBK) {
    int ex = sc[t] - hist[t];
    sc[t] = ex;
    offs[k * OROW + t] = ex;
  }
  if (t == 0) offs[k * OROW + NBK] = nk;
  __syncthreads();
#pragma unroll
  for (int j = 0; j < 4; ++j) {
    if (bk[j] >= 0) {
      int pos = sc[bk[j]] + rk[j];
      tmp[k * EPB + pos] = make_int2(key[j], vb[j]);
    }
  }
}

// ---- pass 2: per-(row, col-octant) counting sort within each 256-row bucket.
// Produces edges ordered by col-range within each row, packed u8 per-octant
// counts (cnt8), and the row base offset. Octant = col >> 14 (7 x 2MB of x).
__global__ __launch_bounds__(512) void build_csr(
    const int2* __restrict__ tmp, const int* __restrict__ offs,
    int2* __restrict__ edges, int* __restrict__ row_beg,
    int2* __restrict__ cnt8) {
  __shared__ int hist[RPB * 8];
  __shared__ int cur[RPB * 8];
  __shared__ int sc[RPB];
  int b = blockIdx.x;
  int t = threadIdx.x;
  int o8 = t >> 3;         // 64 octets per block
  int ol = t & 7;
  for (int i = t; i < RPB * 8; i += 512) hist[i] = 0;
  __syncthreads();
  for (int k = o8; k < KBLK; k += 64) {
    int o0 = offs[k * OROW + b];
    int o1 = offs[k * OROW + b + 1];
    const int2* seg = tmp + k * EPB;
    for (int i = o0 + ol; i < o1; i += 8) {
      int key = seg[i].x;
      atomicAdd(&hist[((key >> 17) << 3) | ((key >> 14) & 7)], 1);
    }
  }
  __syncthreads();
  int v = 0, v2 = 0;
  if (t < RPB) {
#pragma unroll
    for (int o = 0; o < 8; ++o) v += hist[t * 8 + o];
    v2 = (v + 1) & ~1;     // even-padded row length (layout stability)
    sc[t] = v2;
  }
  __syncthreads();
  for (int off = 1; off < RPB; off <<= 1) {
    int u = (t >= off && t < RPB) ? sc[t - off] : 0;
    __syncthreads();
    if (t < RPB) sc[t] += u;
    __syncthreads();
  }
  if (t < RPB) {
    int excl2 = sc[t] - v2;
    int run = excl2;
    unsigned int lo = 0, hi = 0;
#pragma unroll
    for (int o = 0; o < 8; ++o) {
      cur[t * 8 + o] = run;
      int c = hist[t * 8 + o];
      run += c;
      unsigned int cc = (unsigned)(c > 255 ? 255 : c);   // P(clamp) ~ 0
      if (o < 4) lo |= cc << (8 * o); else hi |= cc << (8 * (o - 4));
    }
    int gr = b * RPB + t;
    if (gr < N_NODES) {
      row_beg[gr] = b * CAP + excl2;
      cnt8[gr] = make_int2((int)lo, (int)hi);
    }
  }
  __syncthreads();
  for (int k = o8; k < KBLK; k += 64) {
    int o0 = offs[k * OROW + b];
    int o1 = offs[k * OROW + b + 1];
    const int2* seg = tmp + k * EPB;
    for (int i = o0 + ol; i < o1; i += 8) {
      int2 ed = seg[i];
      int idx = ((ed.x >> 17) << 3) | ((ed.x >> 14) & 7);
      int pos = atomicAdd(&cur[idx], 1);
      edges[b * CAP + pos] = make_int2(ed.x & 0x1FFFF, ed.y);
    }
  }
}

// ---- SpMM, PASS-MAJOR over 7 column ranges (2MB of x each) WITH ILP.
// All 1563 blocks co-resident -> soft-lockstep sweep -> gathers hit the 4MB
// per-XCD L2 ~70% (R5 FETCH_SIZE evidence: 78MB vs ~157MB random).
// R5's regression was the serial per-edge chain; here each thread owns TWO
// rows and each iteration issues up to 4 edge loads + 4 gathers (guarded,
// octet-uniform exec masks -> masked octets issue no requests) before any
// FMA consumes them, restoring ~4 gathers in flight per thread.
__global__ __launch_bounds__(256, 7) void spmm_pass(
    const int* __restrict__ row_beg, const int2* __restrict__ cnt8,
    const int2* __restrict__ edges, const int4* __restrict__ xq,
    int4* __restrict__ h_q, float4* __restrict__ out,
    const int4* __restrict__ add1, const int4* __restrict__ add2,
    int final_mode) {
  int t = threadIdx.x;
  int lane = t & 63;
  int oc = lane >> 3;      // 0..7: row within wave
  int ol = lane & 7;       // 0..7: which 16B of the 128B row
  int w = t >> 6;          // wave 0..3
  int r0 = blockIdx.x * 64 + w * 8 + oc;   // group 0 row
  int r1 = r0 + 32;                        // group 1 row
  bool val0 = r0 < N_NODES, val1 = r1 < N_NODES;
  int off0 = 0, off1 = 0;
  int2 k0 = make_int2(0, 0), k1 = make_int2(0, 0);
  if (val0) { off0 = row_beg[r0]; k0 = cnt8[r0]; }
  if (val1) { off1 = row_beg[r1]; k1 = cnt8[r1]; }
  f32x2 aa0 = {0.f,0.f}, aa1 = {0.f,0.f}, aa2 = {0.f,0.f}, aa3 = {0.f,0.f};
  f32x2 bb0 = {0.f,0.f}, bb1 = {0.f,0.f}, bb2 = {0.f,0.f}, bb3 = {0.f,0.f};

#define GFMA(q0, q1, q2, q3, g, m) { \
    float vv = __int_as_float((m).y); \
    f32x2 vx = {vv, vv}; \
    q0 += vx * upk((g).x); q1 += vx * upk((g).y); \
    q2 += vx * upk((g).z); q3 += vx * upk((g).w); \
  }

#pragma unroll
  for (int p = 0; p < 7; ++p) {
    int c0 = (p < 4 ? (k0.x >> (8 * p)) : (k0.y >> (8 * (p - 4)))) & 255;
    int c1 = (p < 4 ? (k1.x >> (8 * p)) : (k1.y >> (8 * (p - 4)))) & 255;
    int n = c0 > c1 ? c0 : c1;
    for (int i = 0; i < n; i += 2) {
      bool va0 = i < c0, va1 = i + 1 < c0;
      bool vb0 = i < c1, vb1 = i + 1 < c1;
      int2 eA0, eA1, eB0, eB1;
      int4 gA0, gA1, gB0, gB1;
      // issue all edge loads first, then all gathers, then FMAs:
      if (va0) eA0 = edges[off0 + i];
      if (va1) eA1 = edges[off0 + i + 1];
      if (vb0) eB0 = edges[off1 + i];
      if (vb1) eB1 = edges[off1 + i + 1];
      if (va0) gA0 = xq[(size_t)eA0.x * 8 + ol];
      if (va1) gA1 = xq[(size_t)eA1.x * 8 + ol];
      if (vb0) gB0 = xq[(size_t)eB0.x * 8 + ol];
      if (vb1) gB1 = xq[(size_t)eB1.x * 8 + ol];
      if (va0) GFMA(aa0, aa1, aa2, aa3, gA0, eA0);
      if (va1) GFMA(aa0, aa1, aa2, aa3, gA1, eA1);
      if (vb0) GFMA(bb0, bb1, bb2, bb3, gB0, eB0);
      if (vb1) GFMA(bb0, bb1, bb2, bb3, gB1, eB1);
    }
    off0 += c0;
    off1 += c1;
  }
#undef GFMA

#define EPILOG(row, valid, c0v, c1v, c2v, c3v) \
  if (valid) { \
    size_t oi = (size_t)(row) * 8 + ol; \
    if (final_mode) { \
      int4 r1v = add1[oi]; \
      int4 r2v = add2[oi]; \
      float4 lo, hi; \
      lo.x = (c0v).x + ulo(r1v.x) + ulo(r2v.x); \
      lo.y = (c0v).y + uhi(r1v.x) + uhi(r2v.x); \
      lo.z = (c1v).x + ulo(r1v.y) + ulo(r2v.y); \
      lo.w = (c1v).y + uhi(r1v.y) + uhi(r2v.y); \
      hi.x = (c2v).x + ulo(r1v.z) + ulo(r2v.z); \
      hi.y = (c2v).y + uhi(r1v.z) + uhi(r2v.z); \
      hi.z = (c3v).x + ulo(r1v.w) + ulo(r2v.w); \
      hi.w = (c3v).y + uhi(r1v.w) + uhi(r2v.w); \
      out[(size_t)(row) * 16 + ol * 2]     = lo; \
      out[(size_t)(row) * 16 + ol * 2 + 1] = hi; \
    } else { \
      int4 pq; \
      pq.x = pk((c0v).x, (c0v).y); \
      pq.y = pk((c1v).x, (c1v).y); \
      pq.z = pk((c2v).x, (c2v).y); \
      pq.w = pk((c3v).x, (c3v).y); \
      h_q[oi] = pq; \
    } \
  }

  EPILOG(r0, val0, aa0, aa1, aa2, aa3)
  EPILOG(r1, val1, bb0, bb1, bb2, bb3)
#undef EPILOG
}

extern "C" void kernel_launch(void* const* d_in, const int* in_sizes, int n_in,
                              void* d_out, int out_size, void* d_ws, size_t ws_size,
                              hipStream_t stream) {
  const float* x     = (const float*)d_in[0];
  const int*   erow  = (const int*)d_in[1];
  const int*   ecol  = (const int*)d_in[2];
  const float* evals = (const float*)d_in[3];
  float* out = (float*)d_out;

  const size_t hb_bytes   = (size_t)N_NODES * D_FEAT * 2;     // 12.8 MB (bf16)
  const size_t ecap_bytes = (size_t)NBK * CAP * sizeof(int2); // 16.0 MB
  char* ws = (char*)d_ws;
  int4* xbf   = (int4*)(ws);                       // 12.8 MB, live whole launch
  int4* bufA  = (int4*)(ws + hb_bytes);            // h1 (bf16)
  int2* tmp   = (int2*)(ws + hb_bytes);            // aliases bufA (build only)
  int4* bufB  = (int4*)(ws + 2 * hb_bytes);        // h2 (bf16)
  int*  offs  = (int*) (ws + 2 * hb_bytes);        // aliases bufB (build only)
  int2* edges = (int2*)(ws + 3 * hb_bytes);
  int*  row_beg = (int*)(ws + 3 * hb_bytes + ecap_bytes);
  int2* cnt8    = (int2*)(ws + 3 * hb_bytes + ecap_bytes + 400000);  // 800 KB

  // ---- fused convert + bin (1 dispatch), then octant-CSR finalize ----
  convert_bin<<<KBLK + CVB, 1024, 0, stream>>>(
      (const float4*)x, (ushort4*)xbf, erow, ecol, evals, tmp, offs);
  build_csr<<<NBK, 512, 0, stream>>>(tmp, offs, edges, row_beg, cnt8);

  // L1: bufA = bf16(A xbf)      (tmp dead after build)
  spmm_pass<<<SB2, 256, 0, stream>>>(row_beg, cnt8, edges, xbf,
                                     bufA, nullptr, nullptr, nullptr, 0);
  // L2: bufB = bf16(A bufA)     (offs dead)
  spmm_pass<<<SB2, 256, 0, stream>>>(row_beg, cnt8, edges, bufA,
                                     bufB, nullptr, nullptr, nullptr, 0);
  // L3: out = A bufB + bufA + bufB   (f32 output)
  spmm_pass<<<SB2, 256, 0, stream>>>(row_beg, cnt8, edges, bufB,
                                     nullptr, (float4*)out, bufA, bufB, 1);
}

// Round 7
// 255.082 us; speedup vs baseline: 1.1201x; 1.1201x over previous
//
#include <hip/hip_runtime.h>

#define N_NODES 100000
#define N_EDGES 1600000
#define D_FEAT  64

#define RSHIFT 8
#define RPB    256                              // rows per bucket
#define NBK    ((N_NODES + RPB - 1) / RPB)      // 391 row-buckets
#define CAP    6656                             // bucket edge capacity (even; room for per-octant pads)
#define EPB    4096                             // edges per bin block
#define KBLK   ((N_EDGES + EPB - 1) / EPB)      // 391 bin blocks
#define OROW   (NBK + 1)
#define CVB    ((N_NODES * D_FEAT / 4 + 1023) / 1024)  // 1563 convert blocks
#define SB2    ((N_NODES + 63) / 64)            // 1563 spmm blocks (64 rows each)
#define ZPAIR  ((NBK * CAP) >> 1)               // zero-pair slot (past last bucket)

typedef float f32x2 __attribute__((ext_vector_type(2)));

__device__ __forceinline__ unsigned short f2bf(float f) {
  union { float f; unsigned int i; } v; v.f = f;
  unsigned int b = v.i;
  return (unsigned short)((b + 0x7FFFu + ((b >> 16) & 1u)) >> 16);  // RNE
}
__device__ __forceinline__ float ulo(int u) { return __int_as_float(u << 16); }
__device__ __forceinline__ float uhi(int u) { return __int_as_float(u & 0xFFFF0000); }
__device__ __forceinline__ f32x2 upk(int u) {  // {elem0, elem1} of a bf16 pair
  f32x2 r; r.x = ulo(u); r.y = uhi(u); return r;
}
__device__ __forceinline__ int pk(float a, float b) {
  return (int)f2bf(a) | ((int)f2bf(b) << 16);
}

// ---- fused: blocks [0,KBLK) bin edges; blocks [KBLK, KBLK+CVB) convert x ----
__global__ __launch_bounds__(1024) void convert_bin(
    const float4* __restrict__ xin, ushort4* __restrict__ xout,
    const int* __restrict__ erow, const int* __restrict__ ecol,
    const float* __restrict__ evals, int2* __restrict__ tmp,
    int* __restrict__ offs) {
  __shared__ int hist[NBK];
  __shared__ int sc[NBK];
  int t = threadIdx.x;
  int k = blockIdx.x;
  if (k >= KBLK) {                       // ---- convert path ----
    int i = (k - KBLK) * 1024 + t;
    if (i < N_NODES * D_FEAT / 4) {
      float4 v = xin[i];
      ushort4 o;
      o.x = f2bf(v.x); o.y = f2bf(v.y); o.z = f2bf(v.z); o.w = f2bf(v.w);
      xout[i] = o;
    }
    return;
  }
  // ---- bin path: block-local counting sort of 4096 edges by bucket ----
  if (t < NBK) hist[t] = 0;
  __syncthreads();
  int base = k * EPB;
  int nk = N_EDGES - base; if (nk > EPB) nk = EPB;
  int key[4], vb[4], rk[4], bk[4];
#pragma unroll
  for (int j = 0; j < 4; ++j) {
    int li = j * 1024 + t;
    bk[j] = -1;
    if (li < nk) {
      int e = base + li;
      int r = erow[e];
      key[j] = ((r & (RPB - 1)) << 17) | ecol[e];
      vb[j]  = __float_as_int(evals[e]);
      bk[j]  = r >> RSHIFT;
      rk[j]  = atomicAdd(&hist[bk[j]], 1);
    }
  }
  __syncthreads();
  if (t < NBK) sc[t] = hist[t];
  __syncthreads();
  for (int off = 1; off < NBK; off <<= 1) {
    int u = (t >= off && t < NBK) ? sc[t - off] : 0;
    __syncthreads();
    if (t < NBK) sc[t] += u;
    __syncthreads();
  }
  if (t < NBK) {
    int ex = sc[t] - hist[t];
    sc[t] = ex;
    offs[k * OROW + t] = ex;
  }
  if (t == 0) offs[k * OROW + NBK] = nk;
  __syncthreads();
#pragma unroll
  for (int j = 0; j < 4; ++j) {
    if (bk[j] >= 0) {
      int pos = sc[bk[j]] + rk[j];
      tmp[k * EPB + pos] = make_int2(key[j], vb[j]);
    }
  }
}

// ---- pass 2: per-(row, col-octant) counting sort; every octant run is
// padded to an EVEN edge count with {0,0} pairs (val 0 -> adds 0), so spmm
// can walk whole int4 pairs per octant with NO conditional loads.
// cnt8 = packed u8 PAIR counts per octant; row_beg = even edge offset.
__global__ __launch_bounds__(512) void build_csr(
    const int2* __restrict__ tmp, const int* __restrict__ offs,
    int2* __restrict__ edges, int* __restrict__ row_beg,
    int2* __restrict__ cnt8) {
  __shared__ int hist[RPB * 8];
  __shared__ int cur[RPB * 8];
  __shared__ int sc[RPB];
  int b = blockIdx.x;
  int t = threadIdx.x;
  int o8 = t >> 3;         // 64 octets per block
  int ol = t & 7;
  for (int i = t; i < RPB * 8; i += 512) hist[i] = 0;
  __syncthreads();
  for (int k = o8; k < KBLK; k += 64) {
    int o0 = offs[k * OROW + b];
    int o1 = offs[k * OROW + b + 1];
    const int2* seg = tmp + k * EPB;
    for (int i = o0 + ol; i < o1; i += 8) {
      int key = seg[i].x;
      atomicAdd(&hist[((key >> 17) << 3) | ((key >> 14) & 7)], 1);
    }
  }
  __syncthreads();
  int v2 = 0;
  if (t < RPB) {
#pragma unroll
    for (int o = 0; o < 8; ++o) v2 += ((hist[t * 8 + o] + 1) & ~1);
    sc[t] = v2;
  }
  __syncthreads();
  for (int off = 1; off < RPB; off <<= 1) {
    int u = (t >= off && t < RPB) ? sc[t - off] : 0;
    __syncthreads();
    if (t < RPB) sc[t] += u;
    __syncthreads();
  }
  if (t < RPB) {
    int excl2 = sc[t] - v2;
    int run = excl2;
    unsigned int lo = 0, hi = 0;
#pragma unroll
    for (int o = 0; o < 8; ++o) {
      cur[t * 8 + o] = run;
      int c  = hist[t * 8 + o];
      int pc = (c + 1) >> 1;                       // pairs in this run
      if (c & 1) edges[b * CAP + run + c] = make_int2(0, 0);  // pad slot
      unsigned int cc = (unsigned)(pc > 255 ? 255 : pc);      // P(clamp) ~ 0
      if (o < 4) lo |= cc << (8 * o); else hi |= cc << (8 * (o - 4));
      run += pc * 2;
    }
    int gr = b * RPB + t;
    if (gr < N_NODES) {
      row_beg[gr] = b * CAP + excl2;               // even
      cnt8[gr] = make_int2((int)lo, (int)hi);
    }
  }
  if (b == 0 && t == 0) {                          // the shared zero pair
    edges[NBK * CAP]     = make_int2(0, 0);
    edges[NBK * CAP + 1] = make_int2(0, 0);
  }
  __syncthreads();
  for (int k = o8; k < KBLK; k += 64) {
    int o0 = offs[k * OROW + b];
    int o1 = offs[k * OROW + b + 1];
    const int2* seg = tmp + k * EPB;
    for (int i = o0 + ol; i < o1; i += 8) {
      int2 ed = seg[i];
      int idx = ((ed.x >> 17) << 3) | ((ed.x >> 14) & 7);
      int pos = atomicAdd(&cur[idx], 1);
      edges[b * CAP + pos] = make_int2(ed.x & 0x1FFFF, ed.y);
    }
  }
}

// ---- SpMM, PASS-MAJOR over 7 column ranges (2MB of x each), ZERO guarded
// loads. Each thread owns two rows; per iteration: 2 unconditional int4
// pair loads + 4 unconditional int4 gathers (exhausted rows read the shared
// zero pair via v_cndmask'd index -> contribute 0). 1563 blocks co-resident
// (6 blocks/CU at VGPR<=85) sweep the 7 ranges in soft lockstep -> ~70% L2
// hit (R5/R6 FETCH evidence) WITH full issue density (R6's failure fixed).
__global__ __launch_bounds__(256, 6) void spmm_pass(
    const int* __restrict__ row_beg, const int2* __restrict__ cnt8,
    const int4* __restrict__ ep4, const int4* __restrict__ xq,
    int4* __restrict__ h_q, float4* __restrict__ out,
    const int4* __restrict__ add1, const int4* __restrict__ add2,
    int final_mode) {
  int t = threadIdx.x;
  int lane = t & 63;
  int oc = lane >> 3;      // 0..7: row within wave
  int ol = lane & 7;       // 0..7: which 16B of the 128B row
  int w = t >> 6;          // wave 0..3
  int r0 = blockIdx.x * 64 + w * 8 + oc;   // always < N_NODES (max 99999)
  int r1 = r0 + 32;                        // may exceed in last block
  bool v1 = r1 < N_NODES;
  int p0 = row_beg[r0] >> 1;
  int2 k0 = cnt8[r0];
  int p1 = ZPAIR;
  int2 k1 = make_int2(0, 0);
  if (v1) { p1 = row_beg[r1] >> 1; k1 = cnt8[r1]; }
  f32x2 aa0 = {0.f,0.f}, aa1 = {0.f,0.f}, aa2 = {0.f,0.f}, aa3 = {0.f,0.f};
  f32x2 bb0 = {0.f,0.f}, bb1 = {0.f,0.f}, bb2 = {0.f,0.f}, bb3 = {0.f,0.f};

#pragma unroll
  for (int p = 0; p < 7; ++p) {
    int n0 = (p < 4 ? (k0.x >> (8 * p)) : (k0.y >> (8 * (p - 4)))) & 255;
    int n1 = (p < 4 ? (k1.x >> (8 * p)) : (k1.y >> (8 * (p - 4)))) & 255;
    int n = n0 > n1 ? n0 : n1;
    for (int i = 0; i < n; ++i) {
      int i0 = i < n0 ? p0 + i : ZPAIR;    // branchless; load ALWAYS issues
      int i1 = i < n1 ? p1 + i : ZPAIR;
      int4 m0 = ep4[i0];
      int4 m1 = ep4[i1];
      int4 gA0 = xq[(size_t)m0.x * 8 + ol];
      int4 gA1 = xq[(size_t)m0.z * 8 + ol];
      int4 gB0 = xq[(size_t)m1.x * 8 + ol];
      int4 gB1 = xq[(size_t)m1.z * 8 + ol];
      float va0 = __int_as_float(m0.y), va1 = __int_as_float(m0.w);
      f32x2 vA0 = {va0, va0}, vA1 = {va1, va1};
      aa0 += vA0 * upk(gA0.x) + vA1 * upk(gA1.x);
      aa1 += vA0 * upk(gA0.y) + vA1 * upk(gA1.y);
      aa2 += vA0 * upk(gA0.z) + vA1 * upk(gA1.z);
      aa3 += vA0 * upk(gA0.w) + vA1 * upk(gA1.w);
      float vb0 = __int_as_float(m1.y), vb1 = __int_as_float(m1.w);
      f32x2 vB0 = {vb0, vb0}, vB1 = {vb1, vb1};
      bb0 += vB0 * upk(gB0.x) + vB1 * upk(gB1.x);
      bb1 += vB0 * upk(gB0.y) + vB1 * upk(gB1.y);
      bb2 += vB0 * upk(gB0.z) + vB1 * upk(gB1.z);
      bb3 += vB0 * upk(gB0.w) + vB1 * upk(gB1.w);
    }
    p0 += n0;
    p1 += n1;
  }

#define EPILOG(row, valid, c0v, c1v, c2v, c3v) \
  if (valid) { \
    size_t oi = (size_t)(row) * 8 + ol; \
    if (final_mode) { \
      int4 r1v = add1[oi]; \
      int4 r2v = add2[oi]; \
      float4 lo, hi; \
      lo.x = (c0v).x + ulo(r1v.x) + ulo(r2v.x); \
      lo.y = (c0v).y + uhi(r1v.x) + uhi(r2v.x); \
      lo.z = (c1v).x + ulo(r1v.y) + ulo(r2v.y); \
      lo.w = (c1v).y + uhi(r1v.y) + uhi(r2v.y); \
      hi.x = (c2v).x + ulo(r1v.z) + ulo(r2v.z); \
      hi.y = (c2v).y + uhi(r1v.z) + uhi(r2v.z); \
      hi.z = (c3v).x + ulo(r1v.w) + ulo(r2v.w); \
      hi.w = (c3v).y + uhi(r1v.w) + uhi(r2v.w); \
      out[(size_t)(row) * 16 + ol * 2]     = lo; \
      out[(size_t)(row) * 16 + ol * 2 + 1] = hi; \
    } else { \
      int4 pq; \
      pq.x = pk((c0v).x, (c0v).y); \
      pq.y = pk((c1v).x, (c1v).y); \
      pq.z = pk((c2v).x, (c2v).y); \
      pq.w = pk((c3v).x, (c3v).y); \
      h_q[oi] = pq; \
    } \
  }

  EPILOG(r0, true, aa0, aa1, aa2, aa3)
  EPILOG(r1, v1,   bb0, bb1, bb2, bb3)
#undef EPILOG
}

extern "C" void kernel_launch(void* const* d_in, const int* in_sizes, int n_in,
                              void* d_out, int out_size, void* d_ws, size_t ws_size,
                              hipStream_t stream) {
  const float* x     = (const float*)d_in[0];
  const int*   erow  = (const int*)d_in[1];
  const int*   ecol  = (const int*)d_in[2];
  const float* evals = (const float*)d_in[3];
  float* out = (float*)d_out;

  const size_t hb_bytes   = (size_t)N_NODES * D_FEAT * 2;     // 12.8 MB (bf16)
  const size_t ecap_bytes = (size_t)NBK * CAP * sizeof(int2) + 16;  // + zero pair
  char* ws = (char*)d_ws;
  int4* xbf   = (int4*)(ws);                       // 12.8 MB, live whole launch
  int4* bufA  = (int4*)(ws + hb_bytes);            // h1 (bf16)
  int2* tmp   = (int2*)(ws + hb_bytes);            // aliases bufA (build only)
  int4* bufB  = (int4*)(ws + 2 * hb_bytes);        // h2 (bf16)
  int*  offs  = (int*) (ws + 2 * hb_bytes);        // aliases bufB (build only)
  int2* edges = (int2*)(ws + 3 * hb_bytes);        // 20.8 MB octant-CSR
  int*  row_beg = (int*)(ws + 3 * hb_bytes + ecap_bytes);
  int2* cnt8    = (int2*)(ws + 3 * hb_bytes + ecap_bytes + 400000);  // 800 KB

  // ---- fused convert + bin (1 dispatch), then octant-CSR finalize ----
  convert_bin<<<KBLK + CVB, 1024, 0, stream>>>(
      (const float4*)x, (ushort4*)xbf, erow, ecol, evals, tmp, offs);
  build_csr<<<NBK, 512, 0, stream>>>(tmp, offs, edges, row_beg, cnt8);

  // L1: bufA = bf16(A xbf)      (tmp dead after build)
  spmm_pass<<<SB2, 256, 0, stream>>>(row_beg, cnt8, (const int4*)edges, xbf,
                                     bufA, nullptr, nullptr, nullptr, 0);
  // L2: bufB = bf16(A bufA)     (offs dead)
  spmm_pass<<<SB2, 256, 0, stream>>>(row_beg, cnt8, (const int4*)edges, bufA,
                                     bufB, nullptr, nullptr, nullptr, 0);
  // L3: out = A bufB + bufA + bufB   (f32 output)
  spmm_pass<<<SB2, 256, 0, stream>>>(row_beg, cnt8, (const int4*)edges, bufB,
                                     nullptr, (float4*)out, bufA, bufB, 1);
}